// Round 4
// baseline (881.422 us; speedup 1.0000x reference)
//
#include <hip/hip_runtime.h>
#include <stdint.h>

#define B_    8
#define N_    20000
#define NPTS  (B_*N_)        // 160000
#define G_    10
#define NPIL  100
#define NSB   (B_*NPIL)      // 800 segments
#define BN_EPS 1e-5f

// ---- workspace layout (bytes) ----
#define OFF_COUNTS   0            // 800*4 = 3200
#define OFF_SUMS     3200         // 2400*4 = 9600
#define ZERO_BYTES   12800
#define OFF_STARTS   12800        // 801*4 -> pad
#define OFF_CURSOR   16064        // 800*4
#define OFF_CENT     19264        // 2400*4
#define OFF_SEG      28864        // 160000*4
#define OFF_W3T      668864       // 128*64*4
#define OFF_W2T      701632       // 64*32*4
#define OFF_W4T      709824       // 768*256*2 bf16 [col][k]
#define OFF_PILBF    1103040      // 800*128*2 bf16
#define OFF_PILW4B   1307840      // 800*768*4 fp32
#define OFF_H3P      3765440      // 160000*128*2 bf16, SORTED rows
#define WS_NEED      44725440

typedef __attribute__((ext_vector_type(8))) short bf16x8;
typedef __attribute__((ext_vector_type(4))) float f32x4;

__device__ __forceinline__ int binidx(float v){
    float t = v + 1.0f;
    t = fminf(fmaxf(t, 0.0f), 1.99f);
    return (int)(t / 0.2f);
}
__device__ __forceinline__ unsigned short f2bf(float f){
    unsigned u = __float_as_uint(f);
    u += 0x7fffu + ((u >> 16) & 1u);
    return (unsigned short)(u >> 16);
}
__device__ __forceinline__ unsigned u16max2(unsigned a, unsigned b){
    unsigned ah=a>>16, bh=b>>16, al=a&0xffffu, bl=b&0xffffu;
    return ((ah>bh?ah:bh)<<16) | (al>bl?al:bl);
}
__device__ __forceinline__ uint4 max16(uint4 a, uint4 b){
    uint4 r; r.x=u16max2(a.x,b.x); r.y=u16max2(a.y,b.y);
    r.z=u16max2(a.z,b.z); r.w=u16max2(a.w,b.w); return r;
}

// ---- kA: pillar id, counts, centroid sums ----
__global__ __launch_bounds__(256) void kA(const float* __restrict__ x,
                                          int* __restrict__ seg,
                                          int* __restrict__ counts,
                                          float* __restrict__ sums){
    int i = blockIdx.x*256 + threadIdx.x;
    if (i >= NPTS) return;
    float x0 = x[3*i], x1 = x[3*i+1], x2 = x[3*i+2];
    int b  = i / N_;
    int iy = binidx(x0), ix = binidx(x2);
    int s  = iy*G_ + ix;
    seg[i] = s;
    int sb = b*NPIL + s;
    atomicAdd(&counts[sb], 1);
    atomicAdd(&sums[sb*3+0], x1);
    atomicAdd(&sums[sb*3+1], x0);
    atomicAdd(&sums[sb*3+2], x2);
}

// ---- kScan: exclusive prefix sum over 800 counts (1 block) ----
__global__ __launch_bounds__(1024) void kScan(const int* __restrict__ counts,
                                              int* __restrict__ starts,
                                              int* __restrict__ cursor){
    __shared__ int s[1024];
    int t = threadIdx.x;
    int c = (t < NSB) ? counts[t] : 0;
    s[t] = c;
    __syncthreads();
    for (int off=1; off<1024; off<<=1){
        int v = (t >= off) ? s[t-off] : 0;
        __syncthreads();
        s[t] += v;
        __syncthreads();
    }
    if (t < NSB){ int st = s[t]-c; starts[t] = st; cursor[t] = st; }
    if (t == NSB) starts[NSB] = s[NSB-1];
}

// ---- kB: centroids + W3T + W2T + W4T ----
__global__ __launch_bounds__(256) void kB(const int* __restrict__ counts,
                                          const float* __restrict__ sums,
                                          float* __restrict__ cent,
                                          const float* __restrict__ W3,
                                          float* __restrict__ W3T,
                                          const float* __restrict__ W2,
                                          float* __restrict__ W2T,
                                          const float* __restrict__ W4,
                                          unsigned short* __restrict__ W4T){
    int idx = blockIdx.x*256 + threadIdx.x;
    if (idx < 2400){
        cent[idx] = sums[idx] / fmaxf((float)counts[idx/3], 1.0f);
    } else if (idx < 2400 + 8192){
        int t = idx - 2400;
        int i = t >> 7, j = t & 127;      // W3[i][j]
        W3T[j*64 + i] = W3[t];
    } else if (idx < 2400 + 8192 + 2048){
        int t = idx - 2400 - 8192;        // t = j*32 + k
        int j = t >> 5, k = t & 31;
        W2T[t] = W2[k*64 + j];
    } else if (idx < 2400 + 8192 + 2048 + 196608){
        int t = idx - 2400 - 8192 - 2048; // t = k*768 + j (coalesced read)
        int k = t / 768, j = t - k*768;
        W4T[j*256 + k] = f2bf(W4[t]);
    }
}

// ---- kC: 2 threads/point MLP; sorted bf16 h3 rows, line-batched stores ----
__global__ __launch_bounds__(512, 4) void kC(const float* __restrict__ x,
                                             const int* __restrict__ seg,
                                             const float* __restrict__ cent,
                                             const float* __restrict__ W1,
                                             const float* __restrict__ W2T,
                                             const float* __restrict__ W3T,
                                             int* __restrict__ cursor,
                                             unsigned short* __restrict__ h3p){
    int t  = blockIdx.x*512 + threadIdx.x;
    int pt = t >> 1, h = t & 1;
    int lane = threadIdx.x & 63;
    int b  = pt / N_;
    int sb = b*NPIL + seg[pt];
    int tmp = 0;
    if (h == 0) tmp = atomicAdd(&cursor[sb], 1);
    int pos = __shfl(tmp, lane & 62, 64);

    float p0 = x[3*pt+1], p1 = x[3*pt], p2 = x[3*pt+2];
    float aug[6];
    aug[0]=p0; aug[1]=p1; aug[2]=p2;
    aug[3]=p0-cent[sb*3+0]; aug[4]=p1-cent[sb*3+1]; aug[5]=p2-cent[sb*3+2];

    float h1[32];
    #pragma unroll
    for (int j=0;j<32;j++){
        float a = 0.f;
        #pragma unroll
        for (int k=0;k<6;k++) a += aug[k]*W1[k*32+j];
        h1[j] = fmaxf(a, 0.f);
    }
    // layer2 split: this thread computes cols h*32..h*32+31; partner has the rest
    float h2own[32], h2oth[32];
    #pragma unroll
    for (int j=0;j<32;j++){
        float a = 0.f;
        const float* w = W2T + (h*32 + j)*32;
        #pragma unroll
        for (int k=0;k<32;k++) a += h1[k]*w[k];
        float o = fmaxf(a, 0.f);
        h2own[j] = o;
        h2oth[j] = __shfl_xor(o, 1);
    }
    // layer3: this thread computes cols h*64 .. h*64+63
    unsigned short* dst = h3p + (size_t)pos*128 + h*64;
    int oo = h*32, ot = (h^1)*32;
    #pragma unroll
    for (int g=0; g<2; g++){
        unsigned buf[16];
        #pragma unroll 4
        for (int jp=0; jp<16; jp++){
            unsigned short two[2];
            #pragma unroll
            for (int e=0; e<2; e++){
                int col = h*64 + g*32 + jp*2 + e;
                const float* w = W3T + col*64;
                float a = 0.f;
                #pragma unroll
                for (int k=0;k<32;k++) a += h2own[k]*w[oo+k];
                #pragma unroll
                for (int k=0;k<32;k++) a += h2oth[k]*w[ot+k];
                two[e] = f2bf(fmaxf(a, 0.f));
            }
            buf[jp] = (unsigned)two[0] | ((unsigned)two[1] << 16);
        }
        uint4* d4 = (uint4*)(dst + g*32);
        #pragma unroll
        for (int q=0;q<4;q++) d4[q] = ((const uint4*)buf)[q];
    }
}

// ---- kM: per-pillar segment-max of h3 (wide loads, LDS tree) ----
__global__ __launch_bounds__(256) void kM(const unsigned short* __restrict__ h3p,
                                          const int* __restrict__ starts,
                                          unsigned short* __restrict__ pilbf){
    __shared__ uint4 sd[16][16];
    int sb = blockIdx.x;
    int tx = threadIdx.x & 15, ty = threadIdx.x >> 4;
    int s = starts[sb], npts = starts[sb+1] - s;
    uint4 acc = {0u,0u,0u,0u};
    for (int p = ty; p < npts; p += 16){
        uint4 v = *(const uint4*)(h3p + (size_t)(s+p)*128 + tx*8);
        acc = max16(acc, v);
    }
    sd[ty][tx] = acc;
    __syncthreads();
    #pragma unroll
    for (int off=8; off; off>>=1){
        if (ty < off) sd[ty][tx] = max16(sd[ty][tx], sd[ty+off][tx]);
        __syncthreads();
    }
    if (ty == 0) *(uint4*)(pilbf + sb*128 + tx*8) = sd[0][tx];
}

// ---- kPB: MFMA GEMM pilW4b[800,768] = pilbf[800,128] @ W4[128:,:] ----
__global__ __launch_bounds__(256) void kPB(const unsigned short* __restrict__ pilbf,
                                           const unsigned short* __restrict__ W4T,
                                           float* __restrict__ pilW4b){
    __shared__ unsigned short Al[128*128];
    __shared__ unsigned short Bl[128*128];
    int m0 = blockIdx.x * 128;
    int n0 = blockIdx.y * 128;
    int tid = threadIdx.x;
    #pragma unroll
    for (int it=0; it<8; it++){
        int cc = tid + it*256;
        int row = cc >> 4, ch = cc & 15;
        int chs = ch ^ (row & 7);
        uint4 v = {0u,0u,0u,0u};
        if (m0 + row < NSB) v = *(const uint4*)(pilbf + (size_t)(m0+row)*128 + chs*8);
        *(uint4*)((char*)Al + cc*16) = v;
        uint4 vb = *(const uint4*)(W4T + (size_t)(n0+row)*256 + 128 + chs*8);
        *(uint4*)((char*)Bl + cc*16) = vb;
    }
    __syncthreads();
    int lane = tid & 63, wid = tid >> 6;
    int wm = wid >> 1, wn = wid & 1;
    int l15 = lane & 15, lhi = lane >> 4;
    f32x4 acc[4][4];
    #pragma unroll
    for (int m=0;m<4;m++)
        #pragma unroll
        for (int n=0;n<4;n++) acc[m][n] = (f32x4){0.f,0.f,0.f,0.f};
    #pragma unroll
    for (int kk=0; kk<4; kk++){
        bf16x8 af[4], bfr[4];
        #pragma unroll
        for (int f=0; f<4; f++){
            int ra = wm*64 + f*16 + l15;
            af[f]  = *(const bf16x8*)((char*)Al + ra*256 + (((kk*4+lhi) ^ (ra&7))*16));
            int rb = wn*64 + f*16 + l15;
            bfr[f] = *(const bf16x8*)((char*)Bl + rb*256 + (((kk*4+lhi) ^ (rb&7))*16));
        }
        #pragma unroll
        for (int m=0;m<4;m++)
            #pragma unroll
            for (int n=0;n<4;n++)
                acc[m][n] = __builtin_amdgcn_mfma_f32_16x16x32_bf16(af[m], bfr[n], acc[m][n], 0,0,0);
    }
    #pragma unroll
    for (int m=0;m<4;m++)
        #pragma unroll
        for (int r=0;r<4;r++){
            int p = wm*64 + m*16 + lhi*4 + r;
            int sbp = m0 + p;
            if (sbp < NSB){
                #pragma unroll
                for (int n=0;n<4;n++)
                    pilW4b[(size_t)sbp*768 + n0 + wn*64 + n*16 + l15] = acc[m][n][r];
            }
        }
}

// ---- kD: per-(pillar, coltile) MFMA GEMM K=128 + bias + relu + register segmax ----
__global__ __launch_bounds__(256) void kD(const unsigned short* __restrict__ h3p,
                                          const int* __restrict__ starts,
                                          const float* __restrict__ pilW4b,
                                          const unsigned short* __restrict__ W4T,
                                          float* __restrict__ out){
    __shared__ unsigned short Al[128*128];
    __shared__ unsigned short Bl[128*128];
    __shared__ float red[2][2][64];
    int sb  = blockIdx.x;
    int n0  = blockIdx.y * 128;
    int tid = threadIdx.x;
    int start = starts[sb];
    int npts  = starts[sb+1] - start;
    if (npts == 0){
        if (tid < 128) out[(size_t)sb*768 + n0 + tid] = 0.f;
        return;
    }
    #pragma unroll
    for (int it=0; it<8; it++){
        int cc = tid + it*256;
        int row = cc >> 4, ch = cc & 15;
        int chs = ch ^ (row & 7);
        *(uint4*)((char*)Bl + cc*16) = *(const uint4*)(W4T + (size_t)(n0+row)*256 + chs*8);
    }
    int lane = tid & 63, wid = tid >> 6;
    int wm = wid >> 1, wn = wid & 1;
    int l15 = lane & 15, lhi = lane >> 4;

    float bias[4];
    #pragma unroll
    for (int n=0;n<4;n++) bias[n] = pilW4b[(size_t)sb*768 + n0 + wn*64 + n*16 + l15];

    float mx[4][4][4];
    #pragma unroll
    for (int m=0;m<4;m++)
        #pragma unroll
        for (int n=0;n<4;n++)
            #pragma unroll
            for (int r=0;r<4;r++) mx[m][n][r] = 0.f;

    int nch = (npts + 127) >> 7;
    for (int c=0; c<nch; c++){
        int base = c*128;
        __syncthreads();
        #pragma unroll
        for (int it=0; it<8; it++){
            int cc = tid + it*256;
            int row = cc >> 4, ch = cc & 15;
            int chs = ch ^ (row & 7);
            uint4 v = {0u,0u,0u,0u};
            if (base + row < npts)
                v = *(const uint4*)(h3p + (size_t)(start+base+row)*128 + chs*8);
            *(uint4*)((char*)Al + cc*16) = v;
        }
        __syncthreads();

        f32x4 acc[4][4];
        #pragma unroll
        for (int m=0;m<4;m++)
            #pragma unroll
            for (int n=0;n<4;n++) acc[m][n] = (f32x4){0.f,0.f,0.f,0.f};

        #pragma unroll
        for (int kk=0; kk<4; kk++){
            bf16x8 af[4], bfr[4];
            #pragma unroll
            for (int f=0; f<4; f++){
                int ra = wm*64 + f*16 + l15;
                af[f]  = *(const bf16x8*)((char*)Al + ra*256 + (((kk*4+lhi) ^ (ra&7))*16));
                int rb = wn*64 + f*16 + l15;
                bfr[f] = *(const bf16x8*)((char*)Bl + rb*256 + (((kk*4+lhi) ^ (rb&7))*16));
            }
            #pragma unroll
            for (int m=0;m<4;m++)
                #pragma unroll
                for (int n=0;n<4;n++)
                    acc[m][n] = __builtin_amdgcn_mfma_f32_16x16x32_bf16(af[m], bfr[n], acc[m][n], 0,0,0);
        }

        int nrem = npts - base;
        #pragma unroll
        for (int m=0;m<4;m++)
            #pragma unroll
            for (int r=0;r<4;r++){
                int p = wm*64 + m*16 + lhi*4 + r;
                if (p < nrem){
                    #pragma unroll
                    for (int n=0;n<4;n++)
                        mx[m][n][r] = fmaxf(mx[m][n][r], fmaxf(acc[m][n][r] + bias[n], 0.f));
                }
            }
    }

    float red4[4];
    #pragma unroll
    for (int n=0;n<4;n++){
        float v = 0.f;
        #pragma unroll
        for (int m=0;m<4;m++)
            #pragma unroll
            for (int r=0;r<4;r++) v = fmaxf(v, mx[m][n][r]);
        v = fmaxf(v, __shfl_xor(v, 16));
        v = fmaxf(v, __shfl_xor(v, 32));
        red4[n] = v;
    }
    if (lhi == 0){
        #pragma unroll
        for (int n=0;n<4;n++) red[wm][wn][n*16 + l15] = red4[n];
    }
    __syncthreads();
    if (wm == 0){
        float v = fmaxf(red[0][wn][lane], red[1][wn][lane]);
        out[(size_t)sb*768 + n0 + wn*64 + lane] = v;
    }
}

// ---- kE: per-pillar BatchNorm over (B, 768), in place ----
__global__ __launch_bounds__(256) void kE(float* __restrict__ out,
                                          const float* __restrict__ gamma,
                                          const float* __restrict__ beta){
    int p = blockIdx.x;
    int tid = threadIdx.x;
    float v[B_*3];
    float sum = 0.f, ssq = 0.f;
    #pragma unroll
    for (int b=0;b<B_;b++)
        #pragma unroll
        for (int r=0;r<3;r++){
            float t = out[(b*NPIL + p)*768 + tid + r*256];
            v[b*3+r] = t;
            sum += t; ssq += t*t;
        }
    #pragma unroll
    for (int off=32; off; off>>=1){
        sum += __shfl_xor(sum, off);
        ssq += __shfl_xor(ssq, off);
    }
    __shared__ float ls[8];
    __shared__ float sc[2];
    int lane = tid & 63, w = tid >> 6;
    if (lane == 0){ ls[w] = sum; ls[4+w] = ssq; }
    __syncthreads();
    if (tid == 0){
        float S = ls[0]+ls[1]+ls[2]+ls[3];
        float Q = ls[4]+ls[5]+ls[6]+ls[7];
        float mean = S * (1.0f/6144.0f);
        float var  = Q * (1.0f/6144.0f) - mean*mean;
        float scale = rsqrtf(var + BN_EPS) * gamma[p];
        sc[0] = scale;
        sc[1] = beta[p] - mean*scale;
    }
    __syncthreads();
    float scale = sc[0], shift = sc[1];
    #pragma unroll
    for (int b=0;b<B_;b++)
        #pragma unroll
        for (int r=0;r<3;r++)
            out[(b*NPIL + p)*768 + tid + r*256] = v[b*3+r]*scale + shift;
}

extern "C" void kernel_launch(void* const* d_in, const int* in_sizes, int n_in,
                              void* d_out, int out_size, void* d_ws, size_t ws_size,
                              hipStream_t stream){
    if (ws_size < (size_t)WS_NEED) return;
    const float* x     = (const float*)d_in[0];
    const float* W1    = (const float*)d_in[1];
    const float* W2    = (const float*)d_in[2];
    const float* W3    = (const float*)d_in[3];
    const float* W4    = (const float*)d_in[4];
    const float* gamma = (const float*)d_in[5];
    const float* beta  = (const float*)d_in[6];
    float* out = (float*)d_out;
    char*  ws  = (char*)d_ws;

    int*            counts = (int*)           (ws + OFF_COUNTS);
    float*          sums   = (float*)         (ws + OFF_SUMS);
    int*            starts = (int*)           (ws + OFF_STARTS);
    int*            cursor = (int*)           (ws + OFF_CURSOR);
    float*          cent   = (float*)         (ws + OFF_CENT);
    int*            seg    = (int*)           (ws + OFF_SEG);
    float*          W3T    = (float*)         (ws + OFF_W3T);
    float*          W2T    = (float*)         (ws + OFF_W2T);
    unsigned short* W4T    = (unsigned short*)(ws + OFF_W4T);
    unsigned short* pilbf  = (unsigned short*)(ws + OFF_PILBF);
    float*          pilW4b = (float*)         (ws + OFF_PILW4B);
    unsigned short* h3p    = (unsigned short*)(ws + OFF_H3P);

    hipMemsetAsync(d_ws, 0, ZERO_BYTES, stream);

    kA<<<(NPTS+255)/256, 256, 0, stream>>>(x, seg, counts, sums);
    kScan<<<1, 1024, 0, stream>>>(counts, starts, cursor);
    kB<<<(2400+8192+2048+196608+255)/256, 256, 0, stream>>>(counts, sums, cent, W3, W3T, W2, W2T, W4, W4T);
    kC<<<(2*NPTS)/512, 512, 0, stream>>>(x, seg, cent, W1, W2T, W3T, cursor, h3p);
    kM<<<NSB, 256, 0, stream>>>(h3p, starts, pilbf);
    dim3 gPB((NSB+127)/128, 6);
    kPB<<<gPB, 256, 0, stream>>>(pilbf, W4T, pilW4b);
    dim3 gD(NSB, 6);
    kD<<<gD, 256, 0, stream>>>(h3p, starts, pilW4b, W4T, out);
    kE<<<NPIL, 256, 0, stream>>>(out, gamma, beta);
}

// Round 5
// 404.278 us; speedup vs baseline: 2.1802x; 2.1802x over previous
//
#include <hip/hip_runtime.h>
#include <stdint.h>

#define B_    8
#define N_    20000
#define NPTS  (B_*N_)        // 160000
#define G_    10
#define NPIL  100
#define NSB   (B_*NPIL)      // 800 segments
#define BN_EPS 1e-5f

// ---- workspace layout (bytes) ----
#define OFF_COUNTS   0            // 800*4 = 3200
#define OFF_SUMS     3200         // 2400*4 = 9600
#define ZERO_BYTES   12800
#define OFF_STARTS   12800        // 801*4 -> pad
#define OFF_CURSOR   16064        // 800*4
#define OFF_CENT     19264        // 2400*4
#define OFF_SEG      28864        // 160000*4
#define OFF_W3T      668864       // 128*64*4
#define OFF_W4T      709824       // 768*256*2 bf16 [col][k]
#define OFF_PILBF    1103040      // 800*128*2 bf16
#define OFF_PILW4B   1307840      // 800*768*4 fp32
#define OFF_H3P      3765440      // 160000*128*2 bf16, SORTED rows
#define WS_NEED      44725440

typedef __attribute__((ext_vector_type(8))) short bf16x8;
typedef __attribute__((ext_vector_type(4))) float f32x4;

__device__ __forceinline__ int binidx(float v){
    float t = v + 1.0f;
    t = fminf(fmaxf(t, 0.0f), 1.99f);
    return (int)(t / 0.2f);
}
__device__ __forceinline__ unsigned short f2bf(float f){
    unsigned u = __float_as_uint(f);
    u += 0x7fffu + ((u >> 16) & 1u);
    return (unsigned short)(u >> 16);
}
__device__ __forceinline__ unsigned u16max2(unsigned a, unsigned b){
    unsigned ah=a>>16, bh=b>>16, al=a&0xffffu, bl=b&0xffffu;
    return ((ah>bh?ah:bh)<<16) | (al>bl?al:bl);
}
__device__ __forceinline__ uint4 max16(uint4 a, uint4 b){
    uint4 r; r.x=u16max2(a.x,b.x); r.y=u16max2(a.y,b.y);
    r.z=u16max2(a.z,b.z); r.w=u16max2(a.w,b.w); return r;
}

// ---- kA: pillar id, counts, centroid sums ----
__global__ __launch_bounds__(256) void kA(const float* __restrict__ x,
                                          int* __restrict__ seg,
                                          int* __restrict__ counts,
                                          float* __restrict__ sums){
    int i = blockIdx.x*256 + threadIdx.x;
    if (i >= NPTS) return;
    float x0 = x[3*i], x1 = x[3*i+1], x2 = x[3*i+2];
    int b  = i / N_;
    int iy = binidx(x0), ix = binidx(x2);
    int s  = iy*G_ + ix;
    seg[i] = s;
    int sb = b*NPIL + s;
    atomicAdd(&counts[sb], 1);
    atomicAdd(&sums[sb*3+0], x1);
    atomicAdd(&sums[sb*3+1], x0);
    atomicAdd(&sums[sb*3+2], x2);
}

// ---- kScan: exclusive prefix sum over 800 counts (1 block) ----
__global__ __launch_bounds__(1024) void kScan(const int* __restrict__ counts,
                                              int* __restrict__ starts,
                                              int* __restrict__ cursor){
    __shared__ int s[1024];
    int t = threadIdx.x;
    int c = (t < NSB) ? counts[t] : 0;
    s[t] = c;
    __syncthreads();
    for (int off=1; off<1024; off<<=1){
        int v = (t >= off) ? s[t-off] : 0;
        __syncthreads();
        s[t] += v;
        __syncthreads();
    }
    if (t < NSB){ int st = s[t]-c; starts[t] = st; cursor[t] = st; }
    if (t == NSB) starts[NSB] = s[NSB-1];
}

// ---- kB: centroids + W3T + W4T ----
__global__ __launch_bounds__(256) void kB(const int* __restrict__ counts,
                                          const float* __restrict__ sums,
                                          float* __restrict__ cent,
                                          const float* __restrict__ W3,
                                          float* __restrict__ W3T,
                                          const float* __restrict__ W4,
                                          unsigned short* __restrict__ W4T){
    int idx = blockIdx.x*256 + threadIdx.x;
    if (idx < 2400){
        cent[idx] = sums[idx] / fmaxf((float)counts[idx/3], 1.0f);
    } else if (idx < 2400 + 8192){
        int t = idx - 2400;
        int i = t >> 7, j = t & 127;      // W3[i][j]
        W3T[j*64 + i] = W3[t];
    } else if (idx < 2400 + 8192 + 196608){
        int t = idx - 2400 - 8192;        // t = k*768 + j (coalesced read)
        int k = t / 768, j = t - k*768;
        W4T[j*256 + k] = f2bf(W4[t]);
    }
}

// ---- kC: 1 thread/point MLP 6->32->64->128; full-row register buffer,
//      line-batched stores (64B groups) to kill write amplification ----
__global__ __launch_bounds__(256) void kC(const float* __restrict__ x,
                                          const int* __restrict__ seg,
                                          const float* __restrict__ cent,
                                          const float* __restrict__ W1,
                                          const float* __restrict__ W2,
                                          const float* __restrict__ W3T,
                                          int* __restrict__ cursor,
                                          unsigned short* __restrict__ h3p){
    int i = blockIdx.x*256 + threadIdx.x;
    if (i >= NPTS) return;
    int b  = i / N_;
    int sb = b*NPIL + seg[i];
    int pos = atomicAdd(&cursor[sb], 1);
    float p0 = x[3*i+1], p1 = x[3*i], p2 = x[3*i+2];
    float aug[6];
    aug[0]=p0; aug[1]=p1; aug[2]=p2;
    aug[3]=p0-cent[sb*3+0]; aug[4]=p1-cent[sb*3+1]; aug[5]=p2-cent[sb*3+2];

    float h1[32];
    #pragma unroll
    for (int j=0;j<32;j++){
        float a = 0.f;
        #pragma unroll
        for (int k=0;k<6;k++) a += aug[k]*W1[k*32+j];
        h1[j] = fmaxf(a, 0.f);
    }
    float h2[64];
    #pragma unroll
    for (int j=0;j<64;j++){
        float a = 0.f;
        #pragma unroll
        for (int k=0;k<32;k++) a += h1[k]*W2[k*64+j];
        h2[j] = fmaxf(a, 0.f);
    }
    unsigned short* orow = h3p + (size_t)pos*128;
    #pragma unroll
    for (int half=0; half<2; half++){
        unsigned buf[32];
        #pragma unroll 2
        for (int j0=0;j0<8;j0++){
            #pragma unroll
            for (int jp=0;jp<4;jp++){
                int col = half*64 + j0*8 + jp*2;
                const float* w0 = W3T + (size_t)col*64;
                float a0 = 0.f, a1 = 0.f;
                #pragma unroll
                for (int k=0;k<64;k++){
                    a0 += h2[k]*w0[k];
                    a1 += h2[k]*w0[64+k];
                }
                buf[j0*4+jp] = (unsigned)f2bf(fmaxf(a0,0.f))
                             | ((unsigned)f2bf(fmaxf(a1,0.f)) << 16);
            }
        }
        // 8 consecutive 16B stores -> 128B fully-covered lines
        uint4* d4 = (uint4*)(orow + half*64);
        #pragma unroll
        for (int q=0;q<8;q++) d4[q] = ((const uint4*)buf)[q];
    }
}

// ---- kM: per-pillar segment-max of h3 (wide loads, LDS tree) ----
__global__ __launch_bounds__(256) void kM(const unsigned short* __restrict__ h3p,
                                          const int* __restrict__ starts,
                                          unsigned short* __restrict__ pilbf){
    __shared__ uint4 sd[16][16];
    int sb = blockIdx.x;
    int tx = threadIdx.x & 15, ty = threadIdx.x >> 4;
    int s = starts[sb], npts = starts[sb+1] - s;
    uint4 acc = {0u,0u,0u,0u};
    for (int p = ty; p < npts; p += 16){
        uint4 v = *(const uint4*)(h3p + (size_t)(s+p)*128 + tx*8);
        acc = max16(acc, v);
    }
    sd[ty][tx] = acc;
    __syncthreads();
    #pragma unroll
    for (int off=8; off; off>>=1){
        if (ty < off) sd[ty][tx] = max16(sd[ty][tx], sd[ty+off][tx]);
        __syncthreads();
    }
    if (ty == 0) *(uint4*)(pilbf + sb*128 + tx*8) = sd[0][tx];
}

// ---- kPB: MFMA GEMM pilW4b[800,768] = pilbf[800,128] @ W4[128:,:] ----
__global__ __launch_bounds__(256) void kPB(const unsigned short* __restrict__ pilbf,
                                           const unsigned short* __restrict__ W4T,
                                           float* __restrict__ pilW4b){
    __shared__ unsigned short Al[128*128];
    __shared__ unsigned short Bl[128*128];
    int m0 = blockIdx.x * 128;
    int n0 = blockIdx.y * 128;
    int tid = threadIdx.x;
    #pragma unroll
    for (int it=0; it<8; it++){
        int cc = tid + it*256;
        int row = cc >> 4, ch = cc & 15;
        int chs = ch ^ (row & 7);
        uint4 v = {0u,0u,0u,0u};
        if (m0 + row < NSB) v = *(const uint4*)(pilbf + (size_t)(m0+row)*128 + chs*8);
        *(uint4*)((char*)Al + cc*16) = v;
        uint4 vb = *(const uint4*)(W4T + (size_t)(n0+row)*256 + 128 + chs*8);
        *(uint4*)((char*)Bl + cc*16) = vb;
    }
    __syncthreads();
    int lane = tid & 63, wid = tid >> 6;
    int wm = wid >> 1, wn = wid & 1;
    int l15 = lane & 15, lhi = lane >> 4;
    f32x4 acc[4][4];
    #pragma unroll
    for (int m=0;m<4;m++)
        #pragma unroll
        for (int n=0;n<4;n++) acc[m][n] = (f32x4){0.f,0.f,0.f,0.f};
    #pragma unroll
    for (int kk=0; kk<4; kk++){
        bf16x8 af[4], bfr[4];
        #pragma unroll
        for (int f=0; f<4; f++){
            int ra = wm*64 + f*16 + l15;
            af[f]  = *(const bf16x8*)((char*)Al + ra*256 + (((kk*4+lhi) ^ (ra&7))*16));
            int rb = wn*64 + f*16 + l15;
            bfr[f] = *(const bf16x8*)((char*)Bl + rb*256 + (((kk*4+lhi) ^ (rb&7))*16));
        }
        #pragma unroll
        for (int m=0;m<4;m++)
            #pragma unroll
            for (int n=0;n<4;n++)
                acc[m][n] = __builtin_amdgcn_mfma_f32_16x16x32_bf16(af[m], bfr[n], acc[m][n], 0,0,0);
    }
    #pragma unroll
    for (int m=0;m<4;m++)
        #pragma unroll
        for (int r=0;r<4;r++){
            int p = wm*64 + m*16 + lhi*4 + r;
            int sbp = m0 + p;
            if (sbp < NSB){
                #pragma unroll
                for (int n=0;n<4;n++)
                    pilW4b[(size_t)sbp*768 + n0 + wn*64 + n*16 + l15] = acc[m][n][r];
            }
        }
}

// ---- kD: per-(pillar, coltile) MFMA GEMM K=128 + bias + relu + register segmax ----
__global__ __launch_bounds__(256) void kD(const unsigned short* __restrict__ h3p,
                                          const int* __restrict__ starts,
                                          const float* __restrict__ pilW4b,
                                          const unsigned short* __restrict__ W4T,
                                          float* __restrict__ out){
    __shared__ unsigned short Al[128*128];
    __shared__ unsigned short Bl[128*128];
    __shared__ float red[2][2][64];
    int sb  = blockIdx.x;
    int n0  = blockIdx.y * 128;
    int tid = threadIdx.x;
    int start = starts[sb];
    int npts  = starts[sb+1] - start;
    if (npts == 0){
        if (tid < 128) out[(size_t)sb*768 + n0 + tid] = 0.f;
        return;
    }
    #pragma unroll
    for (int it=0; it<8; it++){
        int cc = tid + it*256;
        int row = cc >> 4, ch = cc & 15;
        int chs = ch ^ (row & 7);
        *(uint4*)((char*)Bl + cc*16) = *(const uint4*)(W4T + (size_t)(n0+row)*256 + chs*8);
    }
    int lane = tid & 63, wid = tid >> 6;
    int wm = wid >> 1, wn = wid & 1;
    int l15 = lane & 15, lhi = lane >> 4;

    float bias[4];
    #pragma unroll
    for (int n=0;n<4;n++) bias[n] = pilW4b[(size_t)sb*768 + n0 + wn*64 + n*16 + l15];

    float mx[4][4][4];
    #pragma unroll
    for (int m=0;m<4;m++)
        #pragma unroll
        for (int n=0;n<4;n++)
            #pragma unroll
            for (int r=0;r<4;r++) mx[m][n][r] = 0.f;

    int nch = (npts + 127) >> 7;
    for (int c=0; c<nch; c++){
        int base = c*128;
        __syncthreads();
        #pragma unroll
        for (int it=0; it<8; it++){
            int cc = tid + it*256;
            int row = cc >> 4, ch = cc & 15;
            int chs = ch ^ (row & 7);
            uint4 v = {0u,0u,0u,0u};
            if (base + row < npts)
                v = *(const uint4*)(h3p + (size_t)(start+base+row)*128 + chs*8);
            *(uint4*)((char*)Al + cc*16) = v;
        }
        __syncthreads();

        f32x4 acc[4][4];
        #pragma unroll
        for (int m=0;m<4;m++)
            #pragma unroll
            for (int n=0;n<4;n++) acc[m][n] = (f32x4){0.f,0.f,0.f,0.f};

        #pragma unroll
        for (int kk=0; kk<4; kk++){
            bf16x8 af[4], bfr[4];
            #pragma unroll
            for (int f=0; f<4; f++){
                int ra = wm*64 + f*16 + l15;
                af[f]  = *(const bf16x8*)((char*)Al + ra*256 + (((kk*4+lhi) ^ (ra&7))*16));
                int rb = wn*64 + f*16 + l15;
                bfr[f] = *(const bf16x8*)((char*)Bl + rb*256 + (((kk*4+lhi) ^ (rb&7))*16));
            }
            #pragma unroll
            for (int m=0;m<4;m++)
                #pragma unroll
                for (int n=0;n<4;n++)
                    acc[m][n] = __builtin_amdgcn_mfma_f32_16x16x32_bf16(af[m], bfr[n], acc[m][n], 0,0,0);
        }

        int nrem = npts - base;
        #pragma unroll
        for (int m=0;m<4;m++)
            #pragma unroll
            for (int r=0;r<4;r++){
                int p = wm*64 + m*16 + lhi*4 + r;
                if (p < nrem){
                    #pragma unroll
                    for (int n=0;n<4;n++)
                        mx[m][n][r] = fmaxf(mx[m][n][r], fmaxf(acc[m][n][r] + bias[n], 0.f));
                }
            }
    }

    float red4[4];
    #pragma unroll
    for (int n=0;n<4;n++){
        float v = 0.f;
        #pragma unroll
        for (int m=0;m<4;m++)
            #pragma unroll
            for (int r=0;r<4;r++) v = fmaxf(v, mx[m][n][r]);
        v = fmaxf(v, __shfl_xor(v, 16));
        v = fmaxf(v, __shfl_xor(v, 32));
        red4[n] = v;
    }
    if (lhi == 0){
        #pragma unroll
        for (int n=0;n<4;n++) red[wm][wn][n*16 + l15] = red4[n];
    }
    __syncthreads();
    if (wm == 0){
        float v = fmaxf(red[0][wn][lane], red[1][wn][lane]);
        out[(size_t)sb*768 + n0 + wn*64 + lane] = v;
    }
}

// ---- kE: per-pillar BatchNorm over (B, 768), in place ----
__global__ __launch_bounds__(256) void kE(float* __restrict__ out,
                                          const float* __restrict__ gamma,
                                          const float* __restrict__ beta){
    int p = blockIdx.x;
    int tid = threadIdx.x;
    float v[B_*3];
    float sum = 0.f, ssq = 0.f;
    #pragma unroll
    for (int b=0;b<B_;b++)
        #pragma unroll
        for (int r=0;r<3;r++){
            float t = out[(b*NPIL + p)*768 + tid + r*256];
            v[b*3+r] = t;
            sum += t; ssq += t*t;
        }
    #pragma unroll
    for (int off=32; off; off>>=1){
        sum += __shfl_xor(sum, off);
        ssq += __shfl_xor(ssq, off);
    }
    __shared__ float ls[8];
    __shared__ float sc[2];
    int lane = tid & 63, w = tid >> 6;
    if (lane == 0){ ls[w] = sum; ls[4+w] = ssq; }
    __syncthreads();
    if (tid == 0){
        float S = ls[0]+ls[1]+ls[2]+ls[3];
        float Q = ls[4]+ls[5]+ls[6]+ls[7];
        float mean = S * (1.0f/6144.0f);
        float var  = Q * (1.0f/6144.0f) - mean*mean;
        float scale = rsqrtf(var + BN_EPS) * gamma[p];
        sc[0] = scale;
        sc[1] = beta[p] - mean*scale;
    }
    __syncthreads();
    float scale = sc[0], shift = sc[1];
    #pragma unroll
    for (int b=0;b<B_;b++)
        #pragma unroll
        for (int r=0;r<3;r++)
            out[(b*NPIL + p)*768 + tid + r*256] = v[b*3+r]*scale + shift;
}

extern "C" void kernel_launch(void* const* d_in, const int* in_sizes, int n_in,
                              void* d_out, int out_size, void* d_ws, size_t ws_size,
                              hipStream_t stream){
    if (ws_size < (size_t)WS_NEED) return;
    const float* x     = (const float*)d_in[0];
    const float* W1    = (const float*)d_in[1];
    const float* W2    = (const float*)d_in[2];
    const float* W3    = (const float*)d_in[3];
    const float* W4    = (const float*)d_in[4];
    const float* gamma = (const float*)d_in[5];
    const float* beta  = (const float*)d_in[6];
    float* out = (float*)d_out;
    char*  ws  = (char*)d_ws;

    int*            counts = (int*)           (ws + OFF_COUNTS);
    float*          sums   = (float*)         (ws + OFF_SUMS);
    int*            starts = (int*)           (ws + OFF_STARTS);
    int*            cursor = (int*)           (ws + OFF_CURSOR);
    float*          cent   = (float*)         (ws + OFF_CENT);
    int*            seg    = (int*)           (ws + OFF_SEG);
    float*          W3T    = (float*)         (ws + OFF_W3T);
    unsigned short* W4T    = (unsigned short*)(ws + OFF_W4T);
    unsigned short* pilbf  = (unsigned short*)(ws + OFF_PILBF);
    float*          pilW4b = (float*)         (ws + OFF_PILW4B);
    unsigned short* h3p    = (unsigned short*)(ws + OFF_H3P);

    hipMemsetAsync(d_ws, 0, ZERO_BYTES, stream);

    kA<<<(NPTS+255)/256, 256, 0, stream>>>(x, seg, counts, sums);
    kScan<<<1, 1024, 0, stream>>>(counts, starts, cursor);
    kB<<<(2400+8192+196608+255)/256, 256, 0, stream>>>(counts, sums, cent, W3, W3T, W4, W4T);
    kC<<<(NPTS+255)/256, 256, 0, stream>>>(x, seg, cent, W1, W2, W3T, cursor, h3p);
    kM<<<NSB, 256, 0, stream>>>(h3p, starts, pilbf);
    dim3 gPB((NSB+127)/128, 6);
    kPB<<<gPB, 256, 0, stream>>>(pilbf, W4T, pilW4b);
    dim3 gD(NSB, 6);
    kD<<<gD, 256, 0, stream>>>(h3p, starts, pilW4b, W4T, out);
    kE<<<NPIL, 256, 0, stream>>>(out, gamma, beta);
}

// Round 6
// 379.873 us; speedup vs baseline: 2.3203x; 1.0642x over previous
//
#include <hip/hip_runtime.h>
#include <stdint.h>

#define B_    8
#define N_    20000
#define NPTS  (B_*N_)        // 160000
#define G_    10
#define NPIL  100
#define NSB   (B_*NPIL)      // 800 segments
#define BN_EPS 1e-5f

// ---- workspace layout (bytes) ----
#define OFF_COUNTS   0            // 800*4 = 3200
#define OFF_SUMS     3200         // 2400*4 = 9600
#define ZERO_BYTES   12800
#define OFF_STARTS   12800        // 801*4 -> pad
#define OFF_CURSOR   16064        // 800*4
#define OFF_CENT     19264        // 2400*4
#define OFF_SEG      28864        // 160000*4
#define OFF_W3BF     668864       // 128*64*2 bf16 [col][k]
#define OFF_W4T      709824       // 768*256*2 bf16 [col][k]
#define OFF_PILBF    1103040      // 800*128*2 bf16
#define OFF_PILW4B   1307840      // 800*768*4 fp32
#define OFF_H3P      3765440      // 160000*128*2 bf16, SORTED rows (upper half hosts h2 temporarily)
#define WS_NEED      44725440

typedef __attribute__((ext_vector_type(8))) short bf16x8;
typedef __attribute__((ext_vector_type(4))) float f32x4;

__device__ __forceinline__ int binidx(float v){
    float t = v + 1.0f;
    t = fminf(fmaxf(t, 0.0f), 1.99f);
    return (int)(t / 0.2f);
}
__device__ __forceinline__ unsigned short f2bf(float f){
    unsigned u = __float_as_uint(f);
    u += 0x7fffu + ((u >> 16) & 1u);
    return (unsigned short)(u >> 16);
}
__device__ __forceinline__ unsigned u16max2(unsigned a, unsigned b){
    unsigned ah=a>>16, bh=b>>16, al=a&0xffffu, bl=b&0xffffu;
    return ((ah>bh?ah:bh)<<16) | (al>bl?al:bl);
}
__device__ __forceinline__ uint4 max16(uint4 a, uint4 b){
    uint4 r; r.x=u16max2(a.x,b.x); r.y=u16max2(a.y,b.y);
    r.z=u16max2(a.z,b.z); r.w=u16max2(a.w,b.w); return r;
}

// ---- kA: pillar id, counts, centroid sums ----
__global__ __launch_bounds__(256) void kA(const float* __restrict__ x,
                                          int* __restrict__ seg,
                                          int* __restrict__ counts,
                                          float* __restrict__ sums){
    int i = blockIdx.x*256 + threadIdx.x;
    if (i >= NPTS) return;
    float x0 = x[3*i], x1 = x[3*i+1], x2 = x[3*i+2];
    int b  = i / N_;
    int iy = binidx(x0), ix = binidx(x2);
    int s  = iy*G_ + ix;
    seg[i] = s;
    int sb = b*NPIL + s;
    atomicAdd(&counts[sb], 1);
    atomicAdd(&sums[sb*3+0], x1);
    atomicAdd(&sums[sb*3+1], x0);
    atomicAdd(&sums[sb*3+2], x2);
}

// ---- kScan: exclusive prefix sum over 800 counts (1 block) ----
__global__ __launch_bounds__(1024) void kScan(const int* __restrict__ counts,
                                              int* __restrict__ starts,
                                              int* __restrict__ cursor){
    __shared__ int s[1024];
    int t = threadIdx.x;
    int c = (t < NSB) ? counts[t] : 0;
    s[t] = c;
    __syncthreads();
    for (int off=1; off<1024; off<<=1){
        int v = (t >= off) ? s[t-off] : 0;
        __syncthreads();
        s[t] += v;
        __syncthreads();
    }
    if (t < NSB){ int st = s[t]-c; starts[t] = st; cursor[t] = st; }
    if (t == NSB) starts[NSB] = s[NSB-1];
}

// ---- kB: centroids + W3->bf16 [col][k] + W4T ----
__global__ __launch_bounds__(256) void kB(const int* __restrict__ counts,
                                          const float* __restrict__ sums,
                                          float* __restrict__ cent,
                                          const float* __restrict__ W3,
                                          unsigned short* __restrict__ W3bf,
                                          const float* __restrict__ W4,
                                          unsigned short* __restrict__ W4T){
    int idx = blockIdx.x*256 + threadIdx.x;
    if (idx < 2400){
        cent[idx] = sums[idx] / fmaxf((float)counts[idx/3], 1.0f);
    } else if (idx < 2400 + 8192){
        int t = idx - 2400;
        int col = t >> 6, k = t & 63;     // W3[k][col] -> W3bf[col][k]
        W3bf[t] = f2bf(W3[k*128 + col]);
    } else if (idx < 2400 + 8192 + 196608){
        int t = idx - 2400 - 8192;        // t = k*768 + j (coalesced read)
        int k = t / 768, j = t - k*768;
        W4T[j*256 + k] = f2bf(W4[t]);
    }
}

// ---- kC12: per-point layers 1+2 (fp32 VALU), h2 -> bf16 into UPPER half of h3p row ----
__global__ __launch_bounds__(256) void kC12(const float* __restrict__ x,
                                            const int* __restrict__ seg,
                                            const float* __restrict__ cent,
                                            const float* __restrict__ W1,
                                            const float* __restrict__ W2,
                                            int* __restrict__ cursor,
                                            unsigned short* __restrict__ h3p){
    int i = blockIdx.x*256 + threadIdx.x;
    if (i >= NPTS) return;
    int b  = i / N_;
    int sb = b*NPIL + seg[i];
    int pos = atomicAdd(&cursor[sb], 1);
    float p0 = x[3*i+1], p1 = x[3*i], p2 = x[3*i+2];
    float aug[6];
    aug[0]=p0; aug[1]=p1; aug[2]=p2;
    aug[3]=p0-cent[sb*3+0]; aug[4]=p1-cent[sb*3+1]; aug[5]=p2-cent[sb*3+2];

    float h1[32];
    #pragma unroll
    for (int j=0;j<32;j++){
        float a = 0.f;
        #pragma unroll
        for (int k=0;k<6;k++) a += aug[k]*W1[k*32+j];
        h1[j] = fmaxf(a, 0.f);
    }
    unsigned buf[32];
    #pragma unroll 8
    for (int jp=0;jp<32;jp++){
        float a0 = 0.f, a1 = 0.f;
        #pragma unroll
        for (int k=0;k<32;k++){
            a0 += h1[k]*W2[k*64 + jp*2];
            a1 += h1[k]*W2[k*64 + jp*2 + 1];
        }
        buf[jp] = (unsigned)f2bf(fmaxf(a0,0.f)) | ((unsigned)f2bf(fmaxf(a1,0.f)) << 16);
    }
    // 8 consecutive 16B stores -> two fully-covered 64B lines
    uint4* d4 = (uint4*)(h3p + (size_t)pos*128 + 64);
    #pragma unroll
    for (int q=0;q<8;q++) d4[q] = ((const uint4*)buf)[q];
}

// ---- kC3: MFMA GEMM h3[160000,128] = relu(h2[160000,64] @ W3), in place ----
// block 512 thr = 8 waves (4m x 2n), tile 256 rows x 128 cols, K=64.
__global__ __launch_bounds__(512) void kC3(const unsigned short* __restrict__ W3bf,
                                           unsigned short* __restrict__ h3p){
    __shared__ unsigned short Al[256*64];   // 32 KB, row 128B, chunk-swizzled
    __shared__ unsigned short Bl[128*64];   // 16 KB
    int tid = threadIdx.x;
    int m0  = blockIdx.x * 256;
    #pragma unroll
    for (int it=0; it<4; it++){
        int cc = tid + it*512;
        int row = cc >> 3, ch = cc & 7;
        int chs = ch ^ (row & 7);
        *(uint4*)((char*)Al + cc*16) = *(const uint4*)(h3p + (size_t)(m0+row)*128 + 64 + chs*8);
    }
    #pragma unroll
    for (int it=0; it<2; it++){
        int cc = tid + it*512;
        int row = cc >> 3, ch = cc & 7;
        int chs = ch ^ (row & 7);
        *(uint4*)((char*)Bl + cc*16) = *(const uint4*)(W3bf + (size_t)row*64 + chs*8);
    }
    __syncthreads();

    int lane = tid & 63, wid = tid >> 6;
    int wm = wid >> 1, wn = wid & 1;       // 4 x 2 wave grid
    int l15 = lane & 15, lhi = lane >> 4;

    f32x4 acc[4][4];
    #pragma unroll
    for (int m=0;m<4;m++)
        #pragma unroll
        for (int n=0;n<4;n++) acc[m][n] = (f32x4){0.f,0.f,0.f,0.f};

    #pragma unroll
    for (int kk=0; kk<2; kk++){
        bf16x8 af[4], bfr[4];
        #pragma unroll
        for (int f=0; f<4; f++){
            int ra = wm*64 + f*16 + l15;
            af[f]  = *(const bf16x8*)((char*)Al + ra*128 + (((kk*4+lhi) ^ (ra&7))*16));
            int rb = wn*64 + f*16 + l15;
            bfr[f] = *(const bf16x8*)((char*)Bl + rb*128 + (((kk*4+lhi) ^ (rb&7))*16));
        }
        #pragma unroll
        for (int m=0;m<4;m++)
            #pragma unroll
            for (int n=0;n<4;n++)
                acc[m][n] = __builtin_amdgcn_mfma_f32_16x16x32_bf16(af[m], bfr[n], acc[m][n], 0,0,0);
    }

    // relu + store full rows (in place; all LDS staging done before barrier)
    #pragma unroll
    for (int m=0;m<4;m++)
        #pragma unroll
        for (int r=0;r<4;r++){
            int row = m0 + wm*64 + m*16 + lhi*4 + r;
            #pragma unroll
            for (int n=0;n<4;n++){
                int col = wn*64 + n*16 + l15;
                h3p[(size_t)row*128 + col] = f2bf(fmaxf(acc[m][n][r], 0.f));
            }
        }
}

// ---- kM: per-pillar segment-max of h3 (wide loads, LDS tree) ----
__global__ __launch_bounds__(256) void kM(const unsigned short* __restrict__ h3p,
                                          const int* __restrict__ starts,
                                          unsigned short* __restrict__ pilbf){
    __shared__ uint4 sd[16][16];
    int sb = blockIdx.x;
    int tx = threadIdx.x & 15, ty = threadIdx.x >> 4;
    int s = starts[sb], npts = starts[sb+1] - s;
    uint4 acc = {0u,0u,0u,0u};
    for (int p = ty; p < npts; p += 16){
        uint4 v = *(const uint4*)(h3p + (size_t)(s+p)*128 + tx*8);
        acc = max16(acc, v);
    }
    sd[ty][tx] = acc;
    __syncthreads();
    #pragma unroll
    for (int off=8; off; off>>=1){
        if (ty < off) sd[ty][tx] = max16(sd[ty][tx], sd[ty+off][tx]);
        __syncthreads();
    }
    if (ty == 0) *(uint4*)(pilbf + sb*128 + tx*8) = sd[0][tx];
}

// ---- kPB: MFMA GEMM pilW4b[800,768] = pilbf[800,128] @ W4[128:,:] ----
__global__ __launch_bounds__(256) void kPB(const unsigned short* __restrict__ pilbf,
                                           const unsigned short* __restrict__ W4T,
                                           float* __restrict__ pilW4b){
    __shared__ unsigned short Al[128*128];
    __shared__ unsigned short Bl[128*128];
    int m0 = blockIdx.x * 128;
    int n0 = blockIdx.y * 128;
    int tid = threadIdx.x;
    #pragma unroll
    for (int it=0; it<8; it++){
        int cc = tid + it*256;
        int row = cc >> 4, ch = cc & 15;
        int chs = ch ^ (row & 7);
        uint4 v = {0u,0u,0u,0u};
        if (m0 + row < NSB) v = *(const uint4*)(pilbf + (size_t)(m0+row)*128 + chs*8);
        *(uint4*)((char*)Al + cc*16) = v;
        uint4 vb = *(const uint4*)(W4T + (size_t)(n0+row)*256 + 128 + chs*8);
        *(uint4*)((char*)Bl + cc*16) = vb;
    }
    __syncthreads();
    int lane = tid & 63, wid = tid >> 6;
    int wm = wid >> 1, wn = wid & 1;
    int l15 = lane & 15, lhi = lane >> 4;
    f32x4 acc[4][4];
    #pragma unroll
    for (int m=0;m<4;m++)
        #pragma unroll
        for (int n=0;n<4;n++) acc[m][n] = (f32x4){0.f,0.f,0.f,0.f};
    #pragma unroll
    for (int kk=0; kk<4; kk++){
        bf16x8 af[4], bfr[4];
        #pragma unroll
        for (int f=0; f<4; f++){
            int ra = wm*64 + f*16 + l15;
            af[f]  = *(const bf16x8*)((char*)Al + ra*256 + (((kk*4+lhi) ^ (ra&7))*16));
            int rb = wn*64 + f*16 + l15;
            bfr[f] = *(const bf16x8*)((char*)Bl + rb*256 + (((kk*4+lhi) ^ (rb&7))*16));
        }
        #pragma unroll
        for (int m=0;m<4;m++)
            #pragma unroll
            for (int n=0;n<4;n++)
                acc[m][n] = __builtin_amdgcn_mfma_f32_16x16x32_bf16(af[m], bfr[n], acc[m][n], 0,0,0);
    }
    #pragma unroll
    for (int m=0;m<4;m++)
        #pragma unroll
        for (int r=0;r<4;r++){
            int p = wm*64 + m*16 + lhi*4 + r;
            int sbp = m0 + p;
            if (sbp < NSB){
                #pragma unroll
                for (int n=0;n<4;n++)
                    pilW4b[(size_t)sbp*768 + n0 + wn*64 + n*16 + l15] = acc[m][n][r];
            }
        }
}

// ---- kD: per-(pillar, coltile) MFMA GEMM K=128 + bias + relu + register segmax ----
__global__ __launch_bounds__(256) void kD(const unsigned short* __restrict__ h3p,
                                          const int* __restrict__ starts,
                                          const float* __restrict__ pilW4b,
                                          const unsigned short* __restrict__ W4T,
                                          float* __restrict__ out){
    __shared__ unsigned short Al[128*128];
    __shared__ unsigned short Bl[128*128];
    __shared__ float red[2][2][64];
    int sb  = blockIdx.x;
    int n0  = blockIdx.y * 128;
    int tid = threadIdx.x;
    int start = starts[sb];
    int npts  = starts[sb+1] - start;
    if (npts == 0){
        if (tid < 128) out[(size_t)sb*768 + n0 + tid] = 0.f;
        return;
    }
    #pragma unroll
    for (int it=0; it<8; it++){
        int cc = tid + it*256;
        int row = cc >> 4, ch = cc & 15;
        int chs = ch ^ (row & 7);
        *(uint4*)((char*)Bl + cc*16) = *(const uint4*)(W4T + (size_t)(n0+row)*256 + chs*8);
    }
    int lane = tid & 63, wid = tid >> 6;
    int wm = wid >> 1, wn = wid & 1;
    int l15 = lane & 15, lhi = lane >> 4;

    float bias[4];
    #pragma unroll
    for (int n=0;n<4;n++) bias[n] = pilW4b[(size_t)sb*768 + n0 + wn*64 + n*16 + l15];

    float mx[4][4][4];
    #pragma unroll
    for (int m=0;m<4;m++)
        #pragma unroll
        for (int n=0;n<4;n++)
            #pragma unroll
            for (int r=0;r<4;r++) mx[m][n][r] = 0.f;

    int nch = (npts + 127) >> 7;
    for (int c=0; c<nch; c++){
        int base = c*128;
        __syncthreads();
        #pragma unroll
        for (int it=0; it<8; it++){
            int cc = tid + it*256;
            int row = cc >> 4, ch = cc & 15;
            int chs = ch ^ (row & 7);
            uint4 v = {0u,0u,0u,0u};
            if (base + row < npts)
                v = *(const uint4*)(h3p + (size_t)(start+base+row)*128 + chs*8);
            *(uint4*)((char*)Al + cc*16) = v;
        }
        __syncthreads();

        f32x4 acc[4][4];
        #pragma unroll
        for (int m=0;m<4;m++)
            #pragma unroll
            for (int n=0;n<4;n++) acc[m][n] = (f32x4){0.f,0.f,0.f,0.f};

        #pragma unroll
        for (int kk=0; kk<4; kk++){
            bf16x8 af[4], bfr[4];
            #pragma unroll
            for (int f=0; f<4; f++){
                int ra = wm*64 + f*16 + l15;
                af[f]  = *(const bf16x8*)((char*)Al + ra*256 + (((kk*4+lhi) ^ (ra&7))*16));
                int rb = wn*64 + f*16 + l15;
                bfr[f] = *(const bf16x8*)((char*)Bl + rb*256 + (((kk*4+lhi) ^ (rb&7))*16));
            }
            #pragma unroll
            for (int m=0;m<4;m++)
                #pragma unroll
                for (int n=0;n<4;n++)
                    acc[m][n] = __builtin_amdgcn_mfma_f32_16x16x32_bf16(af[m], bfr[n], acc[m][n], 0,0,0);
        }

        int nrem = npts - base;
        #pragma unroll
        for (int m=0;m<4;m++)
            #pragma unroll
            for (int r=0;r<4;r++){
                int p = wm*64 + m*16 + lhi*4 + r;
                if (p < nrem){
                    #pragma unroll
                    for (int n=0;n<4;n++)
                        mx[m][n][r] = fmaxf(mx[m][n][r], fmaxf(acc[m][n][r] + bias[n], 0.f));
                }
            }
    }

    float red4[4];
    #pragma unroll
    for (int n=0;n<4;n++){
        float v = 0.f;
        #pragma unroll
        for (int m=0;m<4;m++)
            #pragma unroll
            for (int r=0;r<4;r++) v = fmaxf(v, mx[m][n][r]);
        v = fmaxf(v, __shfl_xor(v, 16));
        v = fmaxf(v, __shfl_xor(v, 32));
        red4[n] = v;
    }
    if (lhi == 0){
        #pragma unroll
        for (int n=0;n<4;n++) red[wm][wn][n*16 + l15] = red4[n];
    }
    __syncthreads();
    if (wm == 0){
        float v = fmaxf(red[0][wn][lane], red[1][wn][lane]);
        out[(size_t)sb*768 + n0 + wn*64 + lane] = v;
    }
}

// ---- kE: per-pillar BatchNorm over (B, 768), in place ----
__global__ __launch_bounds__(256) void kE(float* __restrict__ out,
                                          const float* __restrict__ gamma,
                                          const float* __restrict__ beta){
    int p = blockIdx.x;
    int tid = threadIdx.x;
    float v[B_*3];
    float sum = 0.f, ssq = 0.f;
    #pragma unroll
    for (int b=0;b<B_;b++)
        #pragma unroll
        for (int r=0;r<3;r++){
            float t = out[(b*NPIL + p)*768 + tid + r*256];
            v[b*3+r] = t;
            sum += t; ssq += t*t;
        }
    #pragma unroll
    for (int off=32; off; off>>=1){
        sum += __shfl_xor(sum, off);
        ssq += __shfl_xor(ssq, off);
    }
    __shared__ float ls[8];
    __shared__ float sc[2];
    int lane = tid & 63, w = tid >> 6;
    if (lane == 0){ ls[w] = sum; ls[4+w] = ssq; }
    __syncthreads();
    if (tid == 0){
        float S = ls[0]+ls[1]+ls[2]+ls[3];
        float Q = ls[4]+ls[5]+ls[6]+ls[7];
        float mean = S * (1.0f/6144.0f);
        float var  = Q * (1.0f/6144.0f) - mean*mean;
        float scale = rsqrtf(var + BN_EPS) * gamma[p];
        sc[0] = scale;
        sc[1] = beta[p] - mean*scale;
    }
    __syncthreads();
    float scale = sc[0], shift = sc[1];
    #pragma unroll
    for (int b=0;b<B_;b++)
        #pragma unroll
        for (int r=0;r<3;r++)
            out[(b*NPIL + p)*768 + tid + r*256] = v[b*3+r]*scale + shift;
}

extern "C" void kernel_launch(void* const* d_in, const int* in_sizes, int n_in,
                              void* d_out, int out_size, void* d_ws, size_t ws_size,
                              hipStream_t stream){
    if (ws_size < (size_t)WS_NEED) return;
    const float* x     = (const float*)d_in[0];
    const float* W1    = (const float*)d_in[1];
    const float* W2    = (const float*)d_in[2];
    const float* W3    = (const float*)d_in[3];
    const float* W4    = (const float*)d_in[4];
    const float* gamma = (const float*)d_in[5];
    const float* beta  = (const float*)d_in[6];
    float* out = (float*)d_out;
    char*  ws  = (char*)d_ws;

    int*            counts = (int*)           (ws + OFF_COUNTS);
    float*          sums   = (float*)         (ws + OFF_SUMS);
    int*            starts = (int*)           (ws + OFF_STARTS);
    int*            cursor = (int*)           (ws + OFF_CURSOR);
    float*          cent   = (float*)         (ws + OFF_CENT);
    int*            seg    = (int*)           (ws + OFF_SEG);
    unsigned short* W3bf   = (unsigned short*)(ws + OFF_W3BF);
    unsigned short* W4T    = (unsigned short*)(ws + OFF_W4T);
    unsigned short* pilbf  = (unsigned short*)(ws + OFF_PILBF);
    float*          pilW4b = (float*)         (ws + OFF_PILW4B);
    unsigned short* h3p    = (unsigned short*)(ws + OFF_H3P);

    hipMemsetAsync(d_ws, 0, ZERO_BYTES, stream);

    kA<<<(NPTS+255)/256, 256, 0, stream>>>(x, seg, counts, sums);
    kScan<<<1, 1024, 0, stream>>>(counts, starts, cursor);
    kB<<<(2400+8192+196608+255)/256, 256, 0, stream>>>(counts, sums, cent, W3, W3bf, W4, W4T);
    kC12<<<(NPTS+255)/256, 256, 0, stream>>>(x, seg, cent, W1, W2, cursor, h3p);
    kC3<<<NPTS/256, 512, 0, stream>>>(W3bf, h3p);
    kM<<<NSB, 256, 0, stream>>>(h3p, starts, pilbf);
    dim3 gPB((NSB+127)/128, 6);
    kPB<<<gPB, 256, 0, stream>>>(pilbf, W4T, pilW4b);
    dim3 gD(NSB, 6);
    kD<<<gD, 256, 0, stream>>>(h3p, starts, pilW4b, W4T, out);
    kE<<<NPIL, 256, 0, stream>>>(out, gamma, beta);
}

// Round 7
// 212.723 us; speedup vs baseline: 4.1435x; 1.7858x over previous
//
#include <hip/hip_runtime.h>
#include <stdint.h>

#define B_    8
#define N_    20000
#define NPTS  (B_*N_)        // 160000
#define G_    10
#define NPIL  100
#define NSB   (B_*NPIL)      // 800 segments
#define BN_EPS 1e-5f

// ---- workspace layout (bytes) ----
#define OFF_COUNTS   0            // 800*4 = 3200
#define OFF_SUMS     3200         // 2400*4 = 9600
#define ZERO_BYTES   12800
#define OFF_STARTS   12800        // 801*4 -> pad
#define OFF_CENT     19264        // 2400*4
#define OFF_SEG      28864        // 160000*4 (packed seg | rank<<10)
#define OFF_W3BF     668864       // 128*64*2 bf16 [col][k]
#define OFF_W4T      709824       // 768*256*2 bf16 [col][k]
#define OFF_PILBF    1103040      // 800*128*2 bf16
#define OFF_PILW4B   1307840      // 800*768*4 fp32
#define OFF_H3P      3765440      // 160000*128*2 bf16, SORTED rows (upper half hosts h2 temporarily)
#define WS_NEED      44725440

typedef __attribute__((ext_vector_type(8))) short bf16x8;
typedef __attribute__((ext_vector_type(4))) float f32x4;

__device__ __forceinline__ int binidx(float v){
    float t = v + 1.0f;
    t = fminf(fmaxf(t, 0.0f), 1.99f);
    return (int)(t / 0.2f);
}
__device__ __forceinline__ unsigned short f2bf(float f){
    unsigned u = __float_as_uint(f);
    u += 0x7fffu + ((u >> 16) & 1u);
    return (unsigned short)(u >> 16);
}
__device__ __forceinline__ unsigned u16max2(unsigned a, unsigned b){
    unsigned ah=a>>16, bh=b>>16, al=a&0xffffu, bl=b&0xffffu;
    return ((ah>bh?ah:bh)<<16) | (al>bl?al:bl);
}
__device__ __forceinline__ uint4 max16(uint4 a, uint4 b){
    uint4 r; r.x=u16max2(a.x,b.x); r.y=u16max2(a.y,b.y);
    r.z=u16max2(a.z,b.z); r.w=u16max2(a.w,b.w); return r;
}

// ---- kA: pillar id + rank (LDS-aggregated counts/sums, 1 global atomic per block-bin) ----
// 256 blocks x 625 contiguous points each.
__global__ __launch_bounds__(256) void kA(const float* __restrict__ x,
                                          int* __restrict__ segrank,
                                          int* __restrict__ counts,
                                          float* __restrict__ sums){
    __shared__ int   lc[NSB];
    __shared__ float lsum[NSB*3];
    __shared__ int   lbase[NSB];
    int tid = threadIdx.x;
    for (int j = tid; j < NSB; j += 256){
        lc[j] = 0;
        lsum[3*j] = 0.f; lsum[3*j+1] = 0.f; lsum[3*j+2] = 0.f;
    }
    __syncthreads();
    int i0 = blockIdx.x * 625;
    int sbv[3], lrv[3];
    float x1v[3];
    #pragma unroll
    for (int t = 0; t < 3; t++){
        int i = i0 + tid + t*256;
        sbv[t] = -1;
        if (tid + t*256 < 625 && i < NPTS){
            float x0 = x[3*i], x1 = x[3*i+1], x2 = x[3*i+2];
            int b  = i / N_;
            int sb = b*NPIL + binidx(x0)*G_ + binidx(x2);
            sbv[t] = sb; x1v[t] = x1;
            lrv[t] = atomicAdd(&lc[sb], 1);
            atomicAdd(&lsum[sb*3+0], x1);
            atomicAdd(&lsum[sb*3+1], x0);
            atomicAdd(&lsum[sb*3+2], x2);
        }
    }
    __syncthreads();
    for (int j = tid; j < NSB; j += 256){
        int c = lc[j];
        if (c > 0){
            lbase[j] = atomicAdd(&counts[j], c);
            atomicAdd(&sums[3*j+0], lsum[3*j+0]);
            atomicAdd(&sums[3*j+1], lsum[3*j+1]);
            atomicAdd(&sums[3*j+2], lsum[3*j+2]);
        }
    }
    __syncthreads();
    #pragma unroll
    for (int t = 0; t < 3; t++){
        if (sbv[t] >= 0){
            int i = i0 + tid + t*256;
            int rank = lbase[sbv[t]] + lrv[t];
            segrank[i] = sbv[t] | (rank << 10);
        }
    }
    (void)x1v;
}

// ---- kScan: exclusive prefix sum over 800 counts (1 block) ----
__global__ __launch_bounds__(1024) void kScan(const int* __restrict__ counts,
                                              int* __restrict__ starts){
    __shared__ int s[1024];
    int t = threadIdx.x;
    int c = (t < NSB) ? counts[t] : 0;
    s[t] = c;
    __syncthreads();
    for (int off=1; off<1024; off<<=1){
        int v = (t >= off) ? s[t-off] : 0;
        __syncthreads();
        s[t] += v;
        __syncthreads();
    }
    if (t < NSB) starts[t] = s[t]-c;
    if (t == NSB) starts[NSB] = s[NSB-1];
}

// ---- kB: centroids + W3->bf16 [col][k] + W4T ----
__global__ __launch_bounds__(256) void kB(const int* __restrict__ counts,
                                          const float* __restrict__ sums,
                                          float* __restrict__ cent,
                                          const float* __restrict__ W3,
                                          unsigned short* __restrict__ W3bf,
                                          const float* __restrict__ W4,
                                          unsigned short* __restrict__ W4T){
    int idx = blockIdx.x*256 + threadIdx.x;
    if (idx < 2400){
        cent[idx] = sums[idx] / fmaxf((float)counts[idx/3], 1.0f);
    } else if (idx < 2400 + 8192){
        int t = idx - 2400;
        int col = t >> 6, k = t & 63;     // W3[k][col] -> W3bf[col][k]
        W3bf[t] = f2bf(W3[k*128 + col]);
    } else if (idx < 2400 + 8192 + 196608){
        int t = idx - 2400 - 8192;        // t = k*768 + j (coalesced read)
        int k = t / 768, j = t - k*768;
        W4T[j*256 + k] = f2bf(W4[t]);
    }
}

// ---- kC12: per-point layers 1+2 (fp32 VALU), h2 -> bf16 into UPPER half of h3p row ----
__global__ __launch_bounds__(256) void kC12(const float* __restrict__ x,
                                            const int* __restrict__ segrank,
                                            const int* __restrict__ starts,
                                            const float* __restrict__ cent,
                                            const float* __restrict__ W1,
                                            const float* __restrict__ W2,
                                            unsigned short* __restrict__ h3p){
    int i = blockIdx.x*256 + threadIdx.x;
    if (i >= NPTS) return;
    int pk = segrank[i];
    int sb = pk & 1023;
    int pos = starts[sb] + (pk >> 10);
    float p0 = x[3*i+1], p1 = x[3*i], p2 = x[3*i+2];
    float aug[6];
    aug[0]=p0; aug[1]=p1; aug[2]=p2;
    aug[3]=p0-cent[sb*3+0]; aug[4]=p1-cent[sb*3+1]; aug[5]=p2-cent[sb*3+2];

    float h1[32];
    #pragma unroll
    for (int j=0;j<32;j++){
        float a = 0.f;
        #pragma unroll
        for (int k=0;k<6;k++) a += aug[k]*W1[k*32+j];
        h1[j] = fmaxf(a, 0.f);
    }
    unsigned buf[32];
    #pragma unroll 8
    for (int jp=0;jp<32;jp++){
        float a0 = 0.f, a1 = 0.f;
        #pragma unroll
        for (int k=0;k<32;k++){
            a0 += h1[k]*W2[k*64 + jp*2];
            a1 += h1[k]*W2[k*64 + jp*2 + 1];
        }
        buf[jp] = (unsigned)f2bf(fmaxf(a0,0.f)) | ((unsigned)f2bf(fmaxf(a1,0.f)) << 16);
    }
    uint4* d4 = (uint4*)(h3p + (size_t)pos*128 + 64);
    #pragma unroll
    for (int q=0;q<8;q++) d4[q] = ((const uint4*)buf)[q];
}

// ---- kC3: MFMA GEMM h3[160000,128] = relu(h2[160000,64] @ W3), in place ----
__global__ __launch_bounds__(512) void kC3(const unsigned short* __restrict__ W3bf,
                                           unsigned short* __restrict__ h3p){
    __shared__ unsigned short Al[256*64];
    __shared__ unsigned short Bl[128*64];
    int tid = threadIdx.x;
    int m0  = blockIdx.x * 256;
    #pragma unroll
    for (int it=0; it<4; it++){
        int cc = tid + it*512;
        int row = cc >> 3, ch = cc & 7;
        int chs = ch ^ (row & 7);
        *(uint4*)((char*)Al + cc*16) = *(const uint4*)(h3p + (size_t)(m0+row)*128 + 64 + chs*8);
    }
    #pragma unroll
    for (int it=0; it<2; it++){
        int cc = tid + it*512;
        int row = cc >> 3, ch = cc & 7;
        int chs = ch ^ (row & 7);
        *(uint4*)((char*)Bl + cc*16) = *(const uint4*)(W3bf + (size_t)row*64 + chs*8);
    }
    __syncthreads();

    int lane = tid & 63, wid = tid >> 6;
    int wm = wid >> 1, wn = wid & 1;
    int l15 = lane & 15, lhi = lane >> 4;

    f32x4 acc[4][4];
    #pragma unroll
    for (int m=0;m<4;m++)
        #pragma unroll
        for (int n=0;n<4;n++) acc[m][n] = (f32x4){0.f,0.f,0.f,0.f};

    #pragma unroll
    for (int kk=0; kk<2; kk++){
        bf16x8 af[4], bfr[4];
        #pragma unroll
        for (int f=0; f<4; f++){
            int ra = wm*64 + f*16 + l15;
            af[f]  = *(const bf16x8*)((char*)Al + ra*128 + (((kk*4+lhi) ^ (ra&7))*16));
            int rb = wn*64 + f*16 + l15;
            bfr[f] = *(const bf16x8*)((char*)Bl + rb*128 + (((kk*4+lhi) ^ (rb&7))*16));
        }
        #pragma unroll
        for (int m=0;m<4;m++)
            #pragma unroll
            for (int n=0;n<4;n++)
                acc[m][n] = __builtin_amdgcn_mfma_f32_16x16x32_bf16(af[m], bfr[n], acc[m][n], 0,0,0);
    }

    #pragma unroll
    for (int m=0;m<4;m++)
        #pragma unroll
        for (int r=0;r<4;r++){
            int row = m0 + wm*64 + m*16 + lhi*4 + r;
            #pragma unroll
            for (int n=0;n<4;n++){
                int col = wn*64 + n*16 + l15;
                h3p[(size_t)row*128 + col] = f2bf(fmaxf(acc[m][n][r], 0.f));
            }
        }
}

// ---- kM: per-pillar segment-max of h3 (wide loads, LDS tree) ----
__global__ __launch_bounds__(256) void kM(const unsigned short* __restrict__ h3p,
                                          const int* __restrict__ starts,
                                          unsigned short* __restrict__ pilbf){
    __shared__ uint4 sd[16][16];
    int sb = blockIdx.x;
    int tx = threadIdx.x & 15, ty = threadIdx.x >> 4;
    int s = starts[sb], npts = starts[sb+1] - s;
    uint4 acc = {0u,0u,0u,0u};
    for (int p = ty; p < npts; p += 16){
        uint4 v = *(const uint4*)(h3p + (size_t)(s+p)*128 + tx*8);
        acc = max16(acc, v);
    }
    sd[ty][tx] = acc;
    __syncthreads();
    #pragma unroll
    for (int off=8; off; off>>=1){
        if (ty < off) sd[ty][tx] = max16(sd[ty][tx], sd[ty+off][tx]);
        __syncthreads();
    }
    if (ty == 0) *(uint4*)(pilbf + sb*128 + tx*8) = sd[0][tx];
}

// ---- kPB: MFMA GEMM pilW4b[800,768] = pilbf[800,128] @ W4[128:,:] ----
__global__ __launch_bounds__(256) void kPB(const unsigned short* __restrict__ pilbf,
                                           const unsigned short* __restrict__ W4T,
                                           float* __restrict__ pilW4b){
    __shared__ unsigned short Al[128*128];
    __shared__ unsigned short Bl[128*128];
    int m0 = blockIdx.x * 128;
    int n0 = blockIdx.y * 128;
    int tid = threadIdx.x;
    #pragma unroll
    for (int it=0; it<8; it++){
        int cc = tid + it*256;
        int row = cc >> 4, ch = cc & 15;
        int chs = ch ^ (row & 7);
        uint4 v = {0u,0u,0u,0u};
        if (m0 + row < NSB) v = *(const uint4*)(pilbf + (size_t)(m0+row)*128 + chs*8);
        *(uint4*)((char*)Al + cc*16) = v;
        uint4 vb = *(const uint4*)(W4T + (size_t)(n0+row)*256 + 128 + chs*8);
        *(uint4*)((char*)Bl + cc*16) = vb;
    }
    __syncthreads();
    int lane = tid & 63, wid = tid >> 6;
    int wm = wid >> 1, wn = wid & 1;
    int l15 = lane & 15, lhi = lane >> 4;
    f32x4 acc[4][4];
    #pragma unroll
    for (int m=0;m<4;m++)
        #pragma unroll
        for (int n=0;n<4;n++) acc[m][n] = (f32x4){0.f,0.f,0.f,0.f};
    #pragma unroll
    for (int kk=0; kk<4; kk++){
        bf16x8 af[4], bfr[4];
        #pragma unroll
        for (int f=0; f<4; f++){
            int ra = wm*64 + f*16 + l15;
            af[f]  = *(const bf16x8*)((char*)Al + ra*256 + (((kk*4+lhi) ^ (ra&7))*16));
            int rb = wn*64 + f*16 + l15;
            bfr[f] = *(const bf16x8*)((char*)Bl + rb*256 + (((kk*4+lhi) ^ (rb&7))*16));
        }
        #pragma unroll
        for (int m=0;m<4;m++)
            #pragma unroll
            for (int n=0;n<4;n++)
                acc[m][n] = __builtin_amdgcn_mfma_f32_16x16x32_bf16(af[m], bfr[n], acc[m][n], 0,0,0);
    }
    #pragma unroll
    for (int m=0;m<4;m++)
        #pragma unroll
        for (int r=0;r<4;r++){
            int p = wm*64 + m*16 + lhi*4 + r;
            int sbp = m0 + p;
            if (sbp < NSB){
                #pragma unroll
                for (int n=0;n<4;n++)
                    pilW4b[(size_t)sbp*768 + n0 + wn*64 + n*16 + l15] = acc[m][n][r];
            }
        }
}

// ---- kD: per-(pillar, coltile) MFMA GEMM K=128 + bias + relu + register segmax ----
__global__ __launch_bounds__(256) void kD(const unsigned short* __restrict__ h3p,
                                          const int* __restrict__ starts,
                                          const float* __restrict__ pilW4b,
                                          const unsigned short* __restrict__ W4T,
                                          float* __restrict__ out){
    __shared__ unsigned short Al[128*128];
    __shared__ unsigned short Bl[128*128];
    __shared__ float red[2][2][64];
    int sb  = blockIdx.x;
    int n0  = blockIdx.y * 128;
    int tid = threadIdx.x;
    int start = starts[sb];
    int npts  = starts[sb+1] - start;
    if (npts == 0){
        if (tid < 128) out[(size_t)sb*768 + n0 + tid] = 0.f;
        return;
    }
    #pragma unroll
    for (int it=0; it<8; it++){
        int cc = tid + it*256;
        int row = cc >> 4, ch = cc & 15;
        int chs = ch ^ (row & 7);
        *(uint4*)((char*)Bl + cc*16) = *(const uint4*)(W4T + (size_t)(n0+row)*256 + chs*8);
    }
    int lane = tid & 63, wid = tid >> 6;
    int wm = wid >> 1, wn = wid & 1;
    int l15 = lane & 15, lhi = lane >> 4;

    float bias[4];
    #pragma unroll
    for (int n=0;n<4;n++) bias[n] = pilW4b[(size_t)sb*768 + n0 + wn*64 + n*16 + l15];

    float mx[4][4][4];
    #pragma unroll
    for (int m=0;m<4;m++)
        #pragma unroll
        for (int n=0;n<4;n++)
            #pragma unroll
            for (int r=0;r<4;r++) mx[m][n][r] = 0.f;

    int nch = (npts + 127) >> 7;
    for (int c=0; c<nch; c++){
        int base = c*128;
        __syncthreads();
        #pragma unroll
        for (int it=0; it<8; it++){
            int cc = tid + it*256;
            int row = cc >> 4, ch = cc & 15;
            int chs = ch ^ (row & 7);
            uint4 v = {0u,0u,0u,0u};
            if (base + row < npts)
                v = *(const uint4*)(h3p + (size_t)(start+base+row)*128 + chs*8);
            *(uint4*)((char*)Al + cc*16) = v;
        }
        __syncthreads();

        f32x4 acc[4][4];
        #pragma unroll
        for (int m=0;m<4;m++)
            #pragma unroll
            for (int n=0;n<4;n++) acc[m][n] = (f32x4){0.f,0.f,0.f,0.f};

        #pragma unroll
        for (int kk=0; kk<4; kk++){
            bf16x8 af[4], bfr[4];
            #pragma unroll
            for (int f=0; f<4; f++){
                int ra = wm*64 + f*16 + l15;
                af[f]  = *(const bf16x8*)((char*)Al + ra*256 + (((kk*4+lhi) ^ (ra&7))*16));
                int rb = wn*64 + f*16 + l15;
                bfr[f] = *(const bf16x8*)((char*)Bl + rb*256 + (((kk*4+lhi) ^ (rb&7))*16));
            }
            #pragma unroll
            for (int m=0;m<4;m++)
                #pragma unroll
                for (int n=0;n<4;n++)
                    acc[m][n] = __builtin_amdgcn_mfma_f32_16x16x32_bf16(af[m], bfr[n], acc[m][n], 0,0,0);
        }

        int nrem = npts - base;
        #pragma unroll
        for (int m=0;m<4;m++)
            #pragma unroll
            for (int r=0;r<4;r++){
                int p = wm*64 + m*16 + lhi*4 + r;
                if (p < nrem){
                    #pragma unroll
                    for (int n=0;n<4;n++)
                        mx[m][n][r] = fmaxf(mx[m][n][r], fmaxf(acc[m][n][r] + bias[n], 0.f));
                }
            }
    }

    float red4[4];
    #pragma unroll
    for (int n=0;n<4;n++){
        float v = 0.f;
        #pragma unroll
        for (int m=0;m<4;m++)
            #pragma unroll
            for (int r=0;r<4;r++) v = fmaxf(v, mx[m][n][r]);
        v = fmaxf(v, __shfl_xor(v, 16));
        v = fmaxf(v, __shfl_xor(v, 32));
        red4[n] = v;
    }
    if (lhi == 0){
        #pragma unroll
        for (int n=0;n<4;n++) red[wm][wn][n*16 + l15] = red4[n];
    }
    __syncthreads();
    if (wm == 0){
        float v = fmaxf(red[0][wn][lane], red[1][wn][lane]);
        out[(size_t)sb*768 + n0 + wn*64 + lane] = v;
    }
}

// ---- kE: per-pillar BatchNorm over (B, 768), in place ----
__global__ __launch_bounds__(256) void kE(float* __restrict__ out,
                                          const float* __restrict__ gamma,
                                          const float* __restrict__ beta){
    int p = blockIdx.x;
    int tid = threadIdx.x;
    float v[B_*3];
    float sum = 0.f, ssq = 0.f;
    #pragma unroll
    for (int b=0;b<B_;b++)
        #pragma unroll
        for (int r=0;r<3;r++){
            float t = out[(b*NPIL + p)*768 + tid + r*256];
            v[b*3+r] = t;
            sum += t; ssq += t*t;
        }
    #pragma unroll
    for (int off=32; off; off>>=1){
        sum += __shfl_xor(sum, off);
        ssq += __shfl_xor(ssq, off);
    }
    __shared__ float ls[8];
    __shared__ float sc[2];
    int lane = tid & 63, w = tid >> 6;
    if (lane == 0){ ls[w] = sum; ls[4+w] = ssq; }
    __syncthreads();
    if (tid == 0){
        float S = ls[0]+ls[1]+ls[2]+ls[3];
        float Q = ls[4]+ls[5]+ls[6]+ls[7];
        float mean = S * (1.0f/6144.0f);
        float var  = Q * (1.0f/6144.0f) - mean*mean;
        float scale = rsqrtf(var + BN_EPS) * gamma[p];
        sc[0] = scale;
        sc[1] = beta[p] - mean*scale;
    }
    __syncthreads();
    float scale = sc[0], shift = sc[1];
    #pragma unroll
    for (int b=0;b<B_;b++)
        #pragma unroll
        for (int r=0;r<3;r++)
            out[(b*NPIL + p)*768 + tid + r*256] = v[b*3+r]*scale + shift;
}

extern "C" void kernel_launch(void* const* d_in, const int* in_sizes, int n_in,
                              void* d_out, int out_size, void* d_ws, size_t ws_size,
                              hipStream_t stream){
    if (ws_size < (size_t)WS_NEED) return;
    const float* x     = (const float*)d_in[0];
    const float* W1    = (const float*)d_in[1];
    const float* W2    = (const float*)d_in[2];
    const float* W3    = (const float*)d_in[3];
    const float* W4    = (const float*)d_in[4];
    const float* gamma = (const float*)d_in[5];
    const float* beta  = (const float*)d_in[6];
    float* out = (float*)d_out;
    char*  ws  = (char*)d_ws;

    int*            counts = (int*)           (ws + OFF_COUNTS);
    float*          sums   = (float*)         (ws + OFF_SUMS);
    int*            starts = (int*)           (ws + OFF_STARTS);
    float*          cent   = (float*)         (ws + OFF_CENT);
    int*            segrank= (int*)           (ws + OFF_SEG);
    unsigned short* W3bf   = (unsigned short*)(ws + OFF_W3BF);
    unsigned short* W4T    = (unsigned short*)(ws + OFF_W4T);
    unsigned short* pilbf  = (unsigned short*)(ws + OFF_PILBF);
    float*          pilW4b = (float*)         (ws + OFF_PILW4B);
    unsigned short* h3p    = (unsigned short*)(ws + OFF_H3P);

    hipMemsetAsync(d_ws, 0, ZERO_BYTES, stream);

    kA<<<256, 256, 0, stream>>>(x, segrank, counts, sums);
    kScan<<<1, 1024, 0, stream>>>(counts, starts);
    kB<<<(2400+8192+196608+255)/256, 256, 0, stream>>>(counts, sums, cent, W3, W3bf, W4, W4T);
    kC12<<<(NPTS+255)/256, 256, 0, stream>>>(x, segrank, starts, cent, W1, W2, h3p);
    kC3<<<NPTS/256, 512, 0, stream>>>(W3bf, h3p);
    kM<<<NSB, 256, 0, stream>>>(h3p, starts, pilbf);
    dim3 gPB((NSB+127)/128, 6);
    kPB<<<gPB, 256, 0, stream>>>(pilbf, W4T, pilW4b);
    dim3 gD(NSB, 6);
    kD<<<gD, 256, 0, stream>>>(h3p, starts, pilW4b, W4T, out);
    kE<<<NPIL, 256, 0, stream>>>(out, gamma, beta);
}